// Round 1
// baseline (1093.915 us; speedup 1.0000x reference)
//
#include <hip/hip_runtime.h>

// NeuralBPDecoder: sparse BP over a 0.1%-dense parity matrix.
// H (8192x16384 fp32, ~134K nonzeros) is parsed once per call into CSR
// (row-major for v->c, col-major for c->v), then 15 iterations of
// gather-sum phases run on transposed (V,B)/(C,B) state for coalesced
// 128B batch-gathers.

#define C_NUM 8192
#define V_NUM 16384
#define B_NUM 32
#define RW 64   // max nnz per row (mean 16.4, Binomial max ~35)
#define CW 32   // max nnz per col (mean 8.2, Binomial max ~22)

__global__ void build_csr(const float* __restrict__ H,
                          int* __restrict__ row_cnt, int* __restrict__ col_cnt,
                          int* __restrict__ row_idx, int* __restrict__ col_idx) {
    const long long total4 = (long long)C_NUM * V_NUM / 4;
    const long long stride = (long long)gridDim.x * blockDim.x;
    for (long long t = (long long)blockIdx.x * blockDim.x + threadIdx.x;
         t < total4; t += stride) {
        float4 hv = ((const float4*)H)[t];
        long long e = t * 4;
        float vals[4] = {hv.x, hv.y, hv.z, hv.w};
#pragma unroll
        for (int k = 0; k < 4; ++k) {
            if (vals[k] != 0.0f) {
                long long ee = e + k;
                int c = (int)(ee >> 14);            // V = 16384 = 2^14
                int v = (int)(ee & (V_NUM - 1));
                int rs = atomicAdd(&row_cnt[c], 1);
                if (rs < RW) row_idx[c * RW + rs] = v;
                int cs = atomicAdd(&col_cnt[v], 1);
                if (cs < CW) col_idx[v * CW + cs] = c;
            }
        }
    }
}

// Transpose llr (B,V)->(V,B) into beliefs + llr_t; syndrome (B,C)->sign (C,B).
__global__ void init_state(const float* __restrict__ llr,
                           const float* __restrict__ synd,
                           float* __restrict__ beliefs, float* __restrict__ llr_t,
                           float* __restrict__ ssign_t) {
    int t = blockIdx.x * blockDim.x + threadIdx.x;
    if (t < V_NUM * B_NUM) {
        int b = t & (B_NUM - 1);
        int v = t >> 5;
        float x = llr[b * V_NUM + v];
        beliefs[t] = x;
        llr_t[t] = x;
    }
    if (t < C_NUM * B_NUM) {
        int b = t & (B_NUM - 1);
        int c = t >> 5;
        ssign_t[t] = 1.0f - 2.0f * synd[b * C_NUM + c];
    }
}

// v->c: c_msg[c,b] = sign[c,b] * tanh(0.5 * w_vc * sum_{v in row c} beliefs[v,b])
__global__ void vc_kernel(const float* __restrict__ beliefs,
                          const int* __restrict__ row_cnt,
                          const int* __restrict__ row_idx,
                          const float* __restrict__ ssign_t,
                          const float* __restrict__ w_vc_p,
                          float* __restrict__ cmsg) {
    int t = blockIdx.x * blockDim.x + threadIdx.x;
    if (t >= C_NUM * B_NUM) return;
    int b = t & (B_NUM - 1);
    int c = t >> 5;
    float w = w_vc_p[0];
    int n = row_cnt[c];
    if (n > RW) n = RW;
    const int* __restrict__ idx = &row_idx[c * RW];
    float sum = 0.0f;
    for (int j = 0; j < n; ++j)
        sum += beliefs[idx[j] * B_NUM + b];   // 32 lanes -> 128B contiguous
    cmsg[t] = ssign_t[t] * tanhf(0.5f * w * sum);
}

// c->v: beliefs_out[v,b] = d*beliefs_in[v,b] + (1-d)*(llr[v,b] + w_cv*sum cmsg[c,b])
__global__ void cv_kernel(const float* __restrict__ cmsg,
                          const int* __restrict__ col_cnt,
                          const int* __restrict__ col_idx,
                          const float* __restrict__ llr_t,
                          const float* __restrict__ beliefs_in,
                          float* __restrict__ beliefs_out,
                          const float* __restrict__ w_cv_p,
                          const float* __restrict__ damping_p) {
    int t = blockIdx.x * blockDim.x + threadIdx.x;
    if (t >= V_NUM * B_NUM) return;
    int b = t & (B_NUM - 1);
    int v = t >> 5;
    float w = w_cv_p[0];
    float d = damping_p[0];
    int n = col_cnt[v];
    if (n > CW) n = CW;
    const int* __restrict__ idx = &col_idx[v * CW];
    float sum = 0.0f;
    for (int j = 0; j < n; ++j)
        sum += cmsg[idx[j] * B_NUM + b];
    beliefs_out[t] = d * beliefs_in[t] + (1.0f - d) * (llr_t[t] + w * sum);
}

// out[b,v] = sigmoid(-beliefs[v,b]) = 1/(1+exp(beliefs))
__global__ void final_kernel(const float* __restrict__ beliefs,
                             float* __restrict__ out) {
    int t = blockIdx.x * blockDim.x + threadIdx.x;
    if (t >= V_NUM * B_NUM) return;
    int v = t & (V_NUM - 1);
    int b = t >> 14;
    float x = beliefs[v * B_NUM + b];
    out[t] = 1.0f / (1.0f + __expf(x));
}

extern "C" void kernel_launch(void* const* d_in, const int* in_sizes, int n_in,
                              void* d_out, int out_size, void* d_ws, size_t ws_size,
                              hipStream_t stream) {
    const float* synd = (const float*)d_in[0];   // (B, C)
    const float* H    = (const float*)d_in[1];   // (C, V)
    const float* llr  = (const float*)d_in[2];   // (B, V)
    const float* w_vc = (const float*)d_in[3];
    const float* w_cv = (const float*)d_in[4];
    const float* damp = (const float*)d_in[5];
    float* out = (float*)d_out;

    // Workspace layout (bytes)
    char* ws = (char*)d_ws;
    size_t off = 0;
    int* row_cnt = (int*)(ws + off); off += (size_t)C_NUM * 4;          // 32 KB
    int* col_cnt = (int*)(ws + off); off += (size_t)V_NUM * 4;          // 64 KB
    int* row_idx = (int*)(ws + off); off += (size_t)C_NUM * RW * 4;     // 2 MB
    int* col_idx = (int*)(ws + off); off += (size_t)V_NUM * CW * 4;     // 2 MB
    float* beliefs_a = (float*)(ws + off); off += (size_t)V_NUM * B_NUM * 4; // 2 MB
    float* beliefs_b = (float*)(ws + off); off += (size_t)V_NUM * B_NUM * 4; // 2 MB
    float* cmsg      = (float*)(ws + off); off += (size_t)C_NUM * B_NUM * 4; // 1 MB
    float* ssign_t   = (float*)(ws + off); off += (size_t)C_NUM * B_NUM * 4; // 1 MB
    float* llr_t     = (float*)(ws + off); off += (size_t)V_NUM * B_NUM * 4; // 2 MB

    // Zero the CSR counters (ws is poisoned 0xAA before every call)
    hipMemsetAsync(row_cnt, 0, (size_t)(C_NUM + V_NUM) * 4, stream);

    build_csr<<<8192, 256, 0, stream>>>(H, row_cnt, col_cnt, row_idx, col_idx);
    init_state<<<(V_NUM * B_NUM + 255) / 256, 256, 0, stream>>>(
        llr, synd, beliefs_a, llr_t, ssign_t);

    float* cur = beliefs_a;
    float* nxt = beliefs_b;
    for (int it = 0; it < 15; ++it) {
        vc_kernel<<<(C_NUM * B_NUM + 255) / 256, 256, 0, stream>>>(
            cur, row_cnt, row_idx, ssign_t, w_vc, cmsg);
        cv_kernel<<<(V_NUM * B_NUM + 255) / 256, 256, 0, stream>>>(
            cmsg, col_cnt, col_idx, llr_t, cur, nxt, w_cv, damp);
        float* tmp = cur; cur = nxt; nxt = tmp;
    }
    final_kernel<<<(V_NUM * B_NUM + 255) / 256, 256, 0, stream>>>(cur, out);
}